// Round 12
// baseline (157.371 us; speedup 1.0000x reference)
//
#include <hip/hip_runtime.h>

#define ES 128
#define KN 50

__device__ __forceinline__ unsigned short f32_to_bf16_rne(float f) {
    unsigned u = __float_as_uint(f);
    unsigned r = u + 0x7FFF + ((u >> 16) & 1);
    return (unsigned short)(r >> 16);
}
__device__ __forceinline__ float bf16_to_f32(unsigned short u) {
    return __uint_as_float(((unsigned)u) << 16);
}

// RWb[r][j] = sum_i rel[r][i] * Wb[i][j]   (f32 — keeps score path exact-ish)
__global__ __launch_bounds__(128) void prep_rwb(
    const float* __restrict__ rel, const float* __restrict__ Wb,
    float* __restrict__ rwb)
{
    const int r = blockIdx.x, j = threadIdx.x;
    float acc = 0.f;
    #pragma unroll 8
    for (int i = 0; i < ES; ++i)
        acc += rel[r * ES + i] * Wb[i * ES + j];
    rwb[r * ES + j] = acc;
}

// WTB row j (bf16): j<128 -> W1^T row j ; j>=128 -> W2^T row j-128
__global__ __launch_bounds__(256) void prep_wtbf(
    const float* __restrict__ W1, const float* __restrict__ W2,
    unsigned short* __restrict__ wtb)
{
    int n = blockIdx.x * 256 + threadIdx.x;   // 0..32767
    int j = n >> 7, c = n & 127;
    const float* src = (j < ES) ? W1 : W2;
    wtb[n] = f32_to_bf16_rne(src[c * ES + (j & 127)]);
}

// rel_emb -> bf16 copy (50 KB, L1-resident for phase A)
__global__ __launch_bounds__(256) void prep_relb(
    const float* __restrict__ rel, unsigned short* __restrict__ relb, int n)
{
    int i = blockIdx.x * 256 + threadIdx.x;
    if (i < n) relb[i] = f32_to_bf16_rne(rel[i]);
}

// Load 5 score rows per half (half0: k=5C+u, half1: k=25+5C+u)
#define LOADC(BUF, C) do {                                                   \
    _Pragma("unroll") for (int u = 0; u < 5; ++u) {                          \
        int row = __shfl(cid, hb + 5 * (C) + u);                             \
        BUF[u] = *(const float4*)(RWb + (size_t)row * ES + 4 * q);           \
    } } while (0)

#define REDUCE(BUF, C) do {                                                  \
    float pv[5];                                                             \
    _Pragma("unroll") for (int u = 0; u < 5; ++u)                            \
        pv[u] = BUF[u].x*wr.x + BUF[u].y*wr.y + BUF[u].z*wr.z + BUF[u].w*wr.w;\
    _Pragma("unroll") for (int s = 1; s < 32; s <<= 1)                       \
        { _Pragma("unroll") for (int u = 0; u < 5; ++u)                      \
            pv[u] += __shfl_xor(pv[u], s); }                                 \
    _Pragma("unroll") for (int u = 0; u < 5; ++u)                            \
        s1 = (q == 5 * (C) + u) ? pv[u] : s1;                                \
    } while (0)

#define XADD(a) do { a.x += __shfl_xor(a.x, 32); a.y += __shfl_xor(a.y, 32); \
                     a.z += __shfl_xor(a.z, 32); a.w += __shfl_xor(a.w, 32); } while (0)

// 4 waves/block, 1 wave per (pair, side). No LDS, no __syncthreads.
// Writes C[orow][0..128)=agg (bf16), C[orow][128..256)=own ent row (bf16).
__global__ __launch_bounds__(256, 4) void onehop_attn(
    const float* __restrict__ ent,
    const int* __restrict__ hidx, const int* __restrict__ tidx,
    const int* __restrict__ conn,
    const float* __restrict__ RWb, const unsigned short* __restrict__ RELB,
    unsigned short* __restrict__ C,
    int npair, int num_ent, int num_rel)
{
    const int tid  = threadIdx.x;
    const int w    = tid >> 6;
    const int lane = tid & 63;
    const int q    = lane & 31;
    const int hi   = lane >> 5;         // half: k-range split
    const int hb   = lane & 32;

    const int gw   = blockIdx.x * 4 + w;        // 0 .. 2*npair-1
    const int pair = min(gw >> 1, npair - 1);
    const int side = gw & 1;                    // 0 = head, 1 = tail

    int hid = min(max(hidx[pair], 0), num_ent - 1);
    int tdi = min(max(tidx[pair], 0), num_ent - 1);
    int eid = side ? tdi : hid;

    float4 he = *(const float4*)(ent + (size_t)hid * ES + 4 * q);
    float4 te = *(const float4*)(ent + (size_t)tdi * ES + 4 * q);
    float4 wr;
    wr.x = te.x - he.x; wr.y = te.y - he.y;
    wr.z = te.z - he.z; wr.w = te.w - he.w;

    // lane (hb+q) holds k = 25*hi + q  (q<25 valid; q>=25 dup k=24)
    const int kl = 25 * hi + min(q, 24);
    int cid = min(max(conn[(size_t)eid * KN + kl], 0), num_rel - 1);

    // ---- Phase S: 50 scores (25 per half), single 5-deep buffer (no spill)
    float s1 = -1e30f;
    {
        float4 buf[5];
        LOADC(buf, 0); REDUCE(buf, 0);
        LOADC(buf, 1); REDUCE(buf, 1);
        LOADC(buf, 2); REDUCE(buf, 2);
        LOADC(buf, 3); REDUCE(buf, 3);
        LOADC(buf, 4); REDUCE(buf, 4);
    }

    // ---- softmax across the full wave (one side's 50 scores)
    float m = s1;
    #pragma unroll
    for (int s = 1; s < 64; s <<= 1) m = fmaxf(m, __shfl_xor(m, s));
    float e1 = __expf(s1 - m);          // invalid lanes (q>=25) -> 0
    float l = e1;
    #pragma unroll
    for (int s = 1; s < 64; s <<= 1) l += __shfl_xor(l, s);
    e1 *= (1.f / l);

    // ---- Phase A: halves process different k simultaneously; bf16 rel rows
    float4 agg = {0.f, 0.f, 0.f, 0.f};
    #pragma unroll 5
    for (int t = 0; t < 25; ++t) {
        int src  = hb + t;              // half hi handles k = 25*hi + t
        float ev = __shfl(e1, src);
        int row  = __shfl(cid, src);
        ushort4 v = *(const ushort4*)(RELB + (size_t)row * ES + 4 * q);
        agg.x += ev * bf16_to_f32(v.x); agg.y += ev * bf16_to_f32(v.y);
        agg.z += ev * bf16_to_f32(v.z); agg.w += ev * bf16_to_f32(v.w);
    }
    XADD(agg);                          // merge the two 25-k halves

    // ---- write C row: lo half -> agg cols [0,128), hi half -> ent cols [128,256)
    const int orow = pair * 2 + side;
    float4 sv = hi ? (side ? te : he) : agg;
    ushort4 o;
    o.x = f32_to_bf16_rne(sv.x); o.y = f32_to_bf16_rne(sv.y);
    o.z = f32_to_bf16_rne(sv.z); o.w = f32_to_bf16_rne(sv.w);
    *(ushort4*)(C + (size_t)orow * 256 + (hi ? 128 : 0) + 4 * q) = o;
}

// out[row][i] = relu( sum_{j<256} C[row][j] * WTB[j][i] + b1[i] + b2[i] )
// 16 rows/block; thread (r, cg): row r, cols cg*8..+8. C-tile in LDS (pad 130).
__global__ __launch_bounds__(256, 4) void gemm_out(
    const unsigned short* __restrict__ C,
    const unsigned short* __restrict__ WTB,
    const float* __restrict__ b1, const float* __restrict__ b2,
    float* __restrict__ out, int nrows)
{
    __shared__ unsigned int Cs[16 * 130];   // 16 rows x 128 uints, pad->conflict-free
    const int tid  = threadIdx.x;
    const int r    = tid >> 4;
    const int cg   = tid & 15;
    const int row0 = blockIdx.x * 16;

    const unsigned int* Cg = (const unsigned int*)(C + (size_t)row0 * 256);
    #pragma unroll
    for (int i = 0; i < 8; ++i) {
        int li = i * 256 + tid;             // 0..2047
        unsigned int v = (row0 + (li >> 7) < nrows) ? Cg[li] : 0u;
        Cs[(li >> 7) * 130 + (li & 127)] = v;
    }
    __syncthreads();

    float acc[8] = {0,0,0,0,0,0,0,0};
    const unsigned int* Wg = (const unsigned int*)WTB;   // row k = 64 uints
    #pragma unroll 4
    for (int k2 = 0; k2 < 128; ++k2) {      // two k per iter (packed in one dword)
        unsigned int cd = Cs[r * 130 + k2];
        float c0 = __uint_as_float(cd << 16);            // k = 2*k2
        float c1 = __uint_as_float(cd & 0xffff0000u);    // k = 2*k2+1
        uint4 w0 = *(const uint4*)(Wg + (size_t)(2 * k2)     * 64 + cg * 4);
        uint4 w1 = *(const uint4*)(Wg + (size_t)(2 * k2 + 1) * 64 + cg * 4);
        acc[0] += c0 * __uint_as_float(w0.x << 16);
        acc[1] += c0 * __uint_as_float(w0.x & 0xffff0000u);
        acc[2] += c0 * __uint_as_float(w0.y << 16);
        acc[3] += c0 * __uint_as_float(w0.y & 0xffff0000u);
        acc[4] += c0 * __uint_as_float(w0.z << 16);
        acc[5] += c0 * __uint_as_float(w0.z & 0xffff0000u);
        acc[6] += c0 * __uint_as_float(w0.w << 16);
        acc[7] += c0 * __uint_as_float(w0.w & 0xffff0000u);
        acc[0] += c1 * __uint_as_float(w1.x << 16);
        acc[1] += c1 * __uint_as_float(w1.x & 0xffff0000u);
        acc[2] += c1 * __uint_as_float(w1.y << 16);
        acc[3] += c1 * __uint_as_float(w1.y & 0xffff0000u);
        acc[4] += c1 * __uint_as_float(w1.z << 16);
        acc[5] += c1 * __uint_as_float(w1.z & 0xffff0000u);
        acc[6] += c1 * __uint_as_float(w1.w << 16);
        acc[7] += c1 * __uint_as_float(w1.w & 0xffff0000u);
    }

    const int col0 = cg * 8;
    float4 p1a = *(const float4*)(b1 + col0);
    float4 p1b = *(const float4*)(b1 + col0 + 4);
    float4 p2a = *(const float4*)(b2 + col0);
    float4 p2b = *(const float4*)(b2 + col0 + 4);
    float4 o0, o1;
    o0.x = fmaxf(acc[0] + p1a.x + p2a.x, 0.f);
    o0.y = fmaxf(acc[1] + p1a.y + p2a.y, 0.f);
    o0.z = fmaxf(acc[2] + p1a.z + p2a.z, 0.f);
    o0.w = fmaxf(acc[3] + p1a.w + p2a.w, 0.f);
    o1.x = fmaxf(acc[4] + p1b.x + p2b.x, 0.f);
    o1.y = fmaxf(acc[5] + p1b.y + p2b.y, 0.f);
    o1.z = fmaxf(acc[6] + p1b.z + p2b.z, 0.f);
    o1.w = fmaxf(acc[7] + p1b.w + p2b.w, 0.f);
    const int row = row0 + r;
    if (row < nrows) {
        *(float4*)(out + (size_t)row * ES + col0)     = o0;
        *(float4*)(out + (size_t)row * ES + col0 + 4) = o1;
    }
}

extern "C" void kernel_launch(void* const* d_in, const int* in_sizes, int n_in,
                              void* d_out, int out_size, void* d_ws, size_t ws_size,
                              hipStream_t stream) {
    const float* ent = (const float*)d_in[0];
    const float* rel = (const float*)d_in[1];
    const float* Wb  = (const float*)d_in[2];
    const float* W1  = (const float*)d_in[3];
    const float* b1  = (const float*)d_in[4];
    const float* W2  = (const float*)d_in[5];
    const float* b2  = (const float*)d_in[6];
    const int* hidx  = (const int*)d_in[7];
    const int* tidx  = (const int*)d_in[8];
    const int* conn  = (const int*)d_in[9];
    float* out = (float*)d_out;

    const int npair   = in_sizes[7];          // 4096
    const int num_ent = in_sizes[0] / ES;     // 100000
    const int num_rel = in_sizes[1] / ES;     // 200
    const int nrows   = 2 * npair;            // 8192 output rows

    // ws layout (ws_size = 256 MiB per fill-counter evidence, round 11):
    //   RWb  f32   [num_rel*128]  = 100 KB
    //   WTB  bf16  [256*128]      =  64 KB
    //   RELB bf16  [num_rel*128]  =  50 KB
    //   C    bf16  [nrows*256]    =   4 MB
    float* rwb = (float*)d_ws;
    unsigned short* wtb  = (unsigned short*)(rwb + (size_t)num_rel * ES);
    unsigned short* relb = wtb + 2 * ES * ES;
    unsigned short* Cm   = relb + (size_t)num_rel * ES;

    prep_rwb<<<num_rel, 128, 0, stream>>>(rel, Wb, rwb);
    prep_wtbf<<<(2 * ES * ES) / 256, 256, 0, stream>>>(W1, W2, wtb);
    prep_relb<<<(num_rel * ES + 255) / 256, 256, 0, stream>>>(rel, relb, num_rel * ES);

    onehop_attn<<<(nrows + 3) / 4, 256, 0, stream>>>(
        ent, hidx, tidx, conn, rwb, relb, Cm, npair, num_ent, num_rel);

    gemm_out<<<(nrows + 15) / 16, 256, 0, stream>>>(
        Cm, wtb, b1, b2, out, nrows);
}

// Round 13
// 146.008 us; speedup vs baseline: 1.0778x; 1.0778x over previous
//
#include <hip/hip_runtime.h>

#define ES 128
#define KN 50

__device__ __forceinline__ unsigned short f32_to_bf16_rne(float f) {
    unsigned u = __float_as_uint(f);
    unsigned r = u + 0x7FFF + ((u >> 16) & 1);
    return (unsigned short)(r >> 16);
}
__device__ __forceinline__ float bf16_to_f32(unsigned short u) {
    return __uint_as_float(((unsigned)u) << 16);
}

// ONE prep launch (3 jobs by blockIdx range):
//   blocks [0,100):    RWb rows 2b,2b+1   (RWb[r][j] = sum_i rel[r][i]*Wb[i][j], f32)
//   blocks [100,228):  WTB bf16 (row j<128: W1^T ; j>=128: W2^T)
//   blocks [228,328):  RELB bf16 copy of rel_emb
__global__ __launch_bounds__(256) void prep_all(
    const float* __restrict__ rel, const float* __restrict__ Wb,
    const float* __restrict__ W1,  const float* __restrict__ W2,
    float* __restrict__ rwb, unsigned short* __restrict__ wtb,
    unsigned short* __restrict__ relb, int num_rel)
{
    const int b = blockIdx.x, tid = threadIdx.x;
    if (b < 100) {
        int r = 2 * b + (tid >> 7);
        int j = tid & 127;
        if (r < num_rel) {
            float acc = 0.f;
            #pragma unroll 8
            for (int i = 0; i < ES; ++i)
                acc += rel[(size_t)r * ES + i] * Wb[i * ES + j];
            rwb[(size_t)r * ES + j] = acc;
        }
    } else if (b < 228) {
        int n = (b - 100) * 256 + tid;          // 0..32767
        int j = n >> 7, c = n & 127;
        const float* src = (j < ES) ? W1 : W2;
        wtb[n] = f32_to_bf16_rne(src[c * ES + (j & 127)]);
    } else {
        int i = (b - 228) * 256 + tid;          // 0..25599
        if (i < num_rel * ES) relb[i] = f32_to_bf16_rne(rel[i]);
    }
}

// Load 5 score rows per half (half0: k=5C+u, half1: k=25+5C+u)
#define LOADC(BUF, C) do {                                                   \
    _Pragma("unroll") for (int u = 0; u < 5; ++u) {                          \
        int row = __shfl(cid, hb + 5 * (C) + u);                             \
        BUF[u] = *(const float4*)(RWb + (size_t)row * ES + 4 * q);           \
    } } while (0)

// Dot + 5-wide batched 5-step butterfly (within each 32-lane half)
#define REDUCE(BUF, C) do {                                                  \
    float pv[5];                                                             \
    _Pragma("unroll") for (int u = 0; u < 5; ++u)                            \
        pv[u] = BUF[u].x*wr.x + BUF[u].y*wr.y + BUF[u].z*wr.z + BUF[u].w*wr.w;\
    _Pragma("unroll") for (int s = 1; s < 32; s <<= 1)                       \
        { _Pragma("unroll") for (int u = 0; u < 5; ++u)                      \
            pv[u] += __shfl_xor(pv[u], s); }                                 \
    _Pragma("unroll") for (int u = 0; u < 5; ++u)                            \
        s1 = (q == 5 * (C) + u) ? pv[u] : s1;                                \
    } while (0)

#define XADD(a) do { a.x += __shfl_xor(a.x, 32); a.y += __shfl_xor(a.y, 32); \
                     a.z += __shfl_xor(a.z, 32); a.w += __shfl_xor(a.w, 32); } while (0)

// 256 threads = 4 waves. Wave w: pair = blk*2 + (w>>1), side = w&1 (independent).
// Final linear: wave w covers j-quarter [64w, 64w+64) for ALL 4 block outputs.
__global__ __launch_bounds__(256, 4) void onehop_main(
    const float* __restrict__ ent, const unsigned short* __restrict__ RELB,
    const float* __restrict__ b1, const float* __restrict__ b2,
    const int* __restrict__ hidx, const int* __restrict__ tidx,
    const int* __restrict__ conn,
    const float* __restrict__ RWb, const unsigned short* __restrict__ WTB,
    float* __restrict__ out, int npair, int num_ent, int num_rel)
{
    __shared__ float coef[4][2 * ES];    // [wave][j<128: agg ; j>=128: own ent row]
    __shared__ float part[4][4][ES];     // [jquarter][output][col]

    const int tid  = threadIdx.x;
    const int w    = tid >> 6;          // wave 0..3
    const int lane = tid & 63;
    const int q    = lane & 31;
    const int hi   = lane >> 5;         // half within wave (k-range split)
    const int hb   = lane & 32;

    const int pair = min(blockIdx.x * 2 + (w >> 1), npair - 1);
    const int side = w & 1;             // 0 = head, 1 = tail

    int hid = min(max(hidx[pair], 0), num_ent - 1);
    int tdi = min(max(tidx[pair], 0), num_ent - 1);
    int eid = side ? tdi : hid;

    float4 he = *(const float4*)(ent + (size_t)hid * ES + 4 * q);
    float4 te = *(const float4*)(ent + (size_t)tdi * ES + 4 * q);
    float4 wr;
    wr.x = te.x - he.x; wr.y = te.y - he.y;
    wr.z = te.z - he.z; wr.w = te.w - he.w;
    if (!hi) *(float4*)(&coef[w][ES + 4 * q]) = side ? te : he;  // W2 coefs

    // k layout: lane (hb + q) holds k = 25*hi + q  (q<25 valid; q>=25 dup k=24)
    const int kl  = 25 * hi + min(q, 24);
    int cid = min(max(conn[(size_t)eid * KN + kl], 0), num_rel - 1);

    // ---- Phase S: 50 scores (25 per half); single 5-deep buffer (no spill)
    float s1 = -1e30f;                  // lane hb+q -> score k = 25*hi + q
    {
        float4 buf[5];
        LOADC(buf, 0); REDUCE(buf, 0);
        LOADC(buf, 1); REDUCE(buf, 1);
        LOADC(buf, 2); REDUCE(buf, 2);
        LOADC(buf, 3); REDUCE(buf, 3);
        LOADC(buf, 4); REDUCE(buf, 4);
    }

    // ---- softmax across the full wave (both halves = one side's 50 scores)
    float m = s1;
    #pragma unroll
    for (int s = 1; s < 64; s <<= 1) m = fmaxf(m, __shfl_xor(m, s));
    float e1 = __expf(s1 - m);          // invalid lanes (q>=25) -> 0
    float l = e1;
    #pragma unroll
    for (int s = 1; s < 64; s <<= 1) l += __shfl_xor(l, s);
    e1 *= (1.f / l);

    // ---- Phase A: halves process different k simultaneously (25 iters, bf16 rows)
    float4 agg = {0.f, 0.f, 0.f, 0.f};
    #pragma unroll 5
    for (int t = 0; t < 25; ++t) {
        int src  = hb + t;              // half hi handles k = 25*hi + t
        float ev = __shfl(e1, src);
        int row  = __shfl(cid, src);
        ushort4 v = *(const ushort4*)(RELB + (size_t)row * ES + 4 * q);
        agg.x += ev * bf16_to_f32(v.x); agg.y += ev * bf16_to_f32(v.y);
        agg.z += ev * bf16_to_f32(v.z); agg.w += ev * bf16_to_f32(v.w);
    }
    XADD(agg);                          // merge the two 25-k halves
    if (!hi) *(float4*)(&coef[w][4 * q]) = agg;
    __syncthreads();

    // ---- Final partials: wave w covers j in [64w, 64w+64) for all 4 outputs
    const int jbase = w << 6;
    float4 a0 = {0,0,0,0}, a1 = {0,0,0,0}, a2 = {0,0,0,0}, a3 = {0,0,0,0};
    #pragma unroll 8
    for (int jj = 0; jj < 32; ++jj) {
        int j0 = jbase + 2 * jj;        // lanes<32: row j0 ; lanes>=32: row j0+1
        ushort4 wv = *(const ushort4*)(WTB + (size_t)j0 * ES + 4 * lane);
        float w0 = bf16_to_f32(wv.x), w1 = bf16_to_f32(wv.y);
        float w2 = bf16_to_f32(wv.z), w3 = bf16_to_f32(wv.w);
        int jl = j0 + hi;
        float c0 = coef[0][jl], c1 = coef[1][jl];
        float c2 = coef[2][jl], c3 = coef[3][jl];
        a0.x += c0*w0; a0.y += c0*w1; a0.z += c0*w2; a0.w += c0*w3;
        a1.x += c1*w0; a1.y += c1*w1; a1.z += c1*w2; a1.w += c1*w3;
        a2.x += c2*w0; a2.y += c2*w1; a2.z += c2*w2; a2.w += c2*w3;
        a3.x += c3*w0; a3.y += c3*w1; a3.z += c3*w2; a3.w += c3*w3;
    }
    XADD(a0); XADD(a1); XADD(a2); XADD(a3);   // combine even/odd-row partials
    if (!hi) {
        *(float4*)(&part[w][0][4 * q]) = a0;
        *(float4*)(&part[w][1][4 * q]) = a1;
        *(float4*)(&part[w][2][4 * q]) = a2;
        *(float4*)(&part[w][3][4 * q]) = a3;
    }
    __syncthreads();

    // ---- epilogue: combine quarters + bias + relu + coalesced float2 store
    const int o = tid >> 6, c2i = tid & 63;
    float px = part[0][o][2*c2i]     + part[1][o][2*c2i]
             + part[2][o][2*c2i]     + part[3][o][2*c2i];
    float py = part[0][o][2*c2i + 1] + part[1][o][2*c2i + 1]
             + part[2][o][2*c2i + 1] + part[3][o][2*c2i + 1];
    float bx = b1[2*c2i]     + b2[2*c2i];
    float by = b1[2*c2i + 1] + b2[2*c2i + 1];
    const int opair = blockIdx.x * 2 + (o >> 1);
    if (opair < npair) {
        float2 r;
        r.x = fmaxf(px + bx, 0.f);
        r.y = fmaxf(py + by, 0.f);
        *(float2*)(out + (size_t)(opair * 2 + (o & 1)) * ES + 2 * c2i) = r;
    }
}

extern "C" void kernel_launch(void* const* d_in, const int* in_sizes, int n_in,
                              void* d_out, int out_size, void* d_ws, size_t ws_size,
                              hipStream_t stream) {
    const float* ent = (const float*)d_in[0];
    const float* rel = (const float*)d_in[1];
    const float* Wb  = (const float*)d_in[2];
    const float* W1  = (const float*)d_in[3];
    const float* b1  = (const float*)d_in[4];
    const float* W2  = (const float*)d_in[5];
    const float* b2  = (const float*)d_in[6];
    const int* hidx  = (const int*)d_in[7];
    const int* tidx  = (const int*)d_in[8];
    const int* conn  = (const int*)d_in[9];
    float* out = (float*)d_out;

    const int npair   = in_sizes[7];          // 4096
    const int num_ent = in_sizes[0] / ES;     // 100000
    const int num_rel = in_sizes[1] / ES;     // 200

    // ws: RWb f32 (100 KB) + WTB bf16 (64 KB) + RELB bf16 (50 KB)
    float* rwb = (float*)d_ws;
    unsigned short* wtb  = (unsigned short*)(rwb + (size_t)num_rel * ES);
    unsigned short* relb = wtb + 2 * ES * ES;

    prep_all<<<328, 256, 0, stream>>>(rel, Wb, W1, W2, rwb, wtb, relb, num_rel);

    const int nblocks = (npair + 1) / 2;      // 2 pairs per block, 4 waves
    onehop_main<<<nblocks, 256, 0, stream>>>(
        ent, relb, b1, b2, hidx, tidx, conn,
        rwb, wtb, out, npair, num_ent, num_rel);
}